// Round 20
// baseline (248.486 us; speedup 1.0000x reference)
//
#include <hip/hip_runtime.h>

typedef unsigned short u16;
typedef unsigned int u32;
typedef __attribute__((ext_vector_type(8))) short s8v;   // 8 bf16 (4 VGPRs) MFMA A/B frag
typedef __attribute__((ext_vector_type(4))) float f4v;   // MFMA C/D frag

#define EMB 1024
#define SEQ 2048
#define BATCH 2
#define HEADS 16
#define HDIM 64
#define HID 4096
#define MROWS 4096   /* BATCH*SEQ */

__device__ __forceinline__ float bf2f(u16 h) {
    u32 u = ((u32)h) << 16;
    union { u32 u; float f; } v; v.u = u; return v.f;
}
__device__ __forceinline__ u16 f2bf(float f) {
    union { float f; u32 u; } v; v.f = f;
    u32 r = v.u + 0x7FFFu + ((v.u >> 16) & 1u);   // RNE
    return (u16)(r >> 16);
}
__device__ __forceinline__ float fexp2(float x) {   // raw v_exp_f32 (2^x)
    float r; asm("v_exp_f32 %0, %1" : "=v"(r) : "v"(x)); return r;
}
__device__ __forceinline__ u32 cvtpk_bf16(float lo, float hi) {   // 2xf32 -> packed bf16
    u32 r; asm("v_cvt_pk_bf16_f32 %0, %1, %2" : "=v"(r) : "v"(lo), "v"(hi)); return r;
}

__device__ __forceinline__ void gload16(const void* g, void* l) {
    __builtin_amdgcn_global_load_lds(
        (const __attribute__((address_space(1))) unsigned int*)g,
        (__attribute__((address_space(3))) unsigned int*)l, 16, 0, 0);
}

// -------- batched transpose + f32->bf16 cast for ALL weights in ONE launch --------
__global__ __launch_bounds__(256) void transpose_all(
        const float* __restrict__ Wq, const float* __restrict__ Wk,
        const float* __restrict__ Wv, const float* __restrict__ Wo,
        const float* __restrict__ W1, const float* __restrict__ W2,
        u16* __restrict__ WqkvT, u16* __restrict__ WoT,
        u16* __restrict__ W1T, u16* __restrict__ W2T) {
    __shared__ float tile[32][33];
    const u32 id = blockIdx.x;
    const float* W;
    u16* WT;
    int K, N, local;
    if (id < 3072) {
        W = (id < 1024) ? Wq : (id < 2048) ? Wk : Wv;
        WT = WqkvT + (size_t)(id >> 10) * 1024 * 1024;
        K = 1024; N = 1024; local = (int)(id & 1023);
    } else if (id < 4096) {
        W = Wo; WT = WoT; K = 1024; N = 1024; local = (int)(id - 3072);
    } else if (id < 8192) {
        W = W1; WT = W1T; K = 1024; N = 4096; local = (int)(id - 4096);
    } else {
        W = W2; WT = W2T; K = 4096; N = 1024; local = (int)(id - 8192);
    }
    const int nx = N / 32;
    const int n0 = (local % nx) * 32, k0 = (local / nx) * 32;
    const int tx = threadIdx.x, ty = threadIdx.y;   // 32 x 8
#pragma unroll
    for (int i = ty; i < 32; i += 8)
        tile[i][tx] = W[(size_t)(k0 + i) * N + n0 + tx];
    __syncthreads();
#pragma unroll
    for (int i = ty; i < 32; i += 8)
        WT[(size_t)(n0 + i) * K + k0 + tx] = f2bf(tile[tx][i]);
}

// ---------------- layernorm f32 -> bf16 ----------------
__global__ __launch_bounds__(256) void ln_kernel(const float* __restrict__ in,
                                                 const float* __restrict__ w,
                                                 const float* __restrict__ b,
                                                 u16* __restrict__ out) {
    const int row = blockIdx.x, t = threadIdx.x;
    const float4* rp = (const float4*)(in + (size_t)row * EMB);
    float4 v = rp[t];
    float s = v.x + v.y + v.z + v.w;
    __shared__ float red[4];
#pragma unroll
    for (int off = 32; off; off >>= 1) s += __shfl_xor(s, off);
    if ((t & 63) == 0) red[t >> 6] = s;
    __syncthreads();
    float mean = (red[0] + red[1] + red[2] + red[3]) * (1.f / EMB);
    float dx = v.x - mean, dy = v.y - mean, dz = v.z - mean, dw = v.w - mean;
    float ss = dx * dx + dy * dy + dz * dz + dw * dw;
#pragma unroll
    for (int off = 32; off; off >>= 1) ss += __shfl_xor(ss, off);
    __syncthreads();
    if ((t & 63) == 0) red[t >> 6] = ss;
    __syncthreads();
    float var = (red[0] + red[1] + red[2] + red[3]) * (1.f / EMB);
    float rstd = rsqrtf(var + 1e-5f);
    float4 wv = ((const float4*)w)[t];
    float4 bv = ((const float4*)b)[t];
    u16* op = out + (size_t)row * EMB + t * 4;
    op[0] = f2bf(dx * rstd * wv.x + bv.x);
    op[1] = f2bf(dy * rstd * wv.y + bv.y);
    op[2] = f2bf(dz * rstd * wv.z + bv.z);
    op[3] = f2bf(dw * rstd * wv.w + bv.w);
}

// ------- bf16 MFMA GEMM, TMxTN tiles, BK-step, dbuf, XCD-swizzled, 2-way LDS swizzle -------
// C[M,N] = A[M,K] @ BT[N,K]^T.  Grid = (N/TN)*(MROWS/TM) blocks, 4 waves in 2x2.
// LDS: linear dest (gload_lds requirement); contents XOR-swizzled via the GLOBAL SOURCE:
//   physical seg = seg ^ ((row>>1) & SM); reads apply the same XOR -> exactly 2-way bank
//   aliasing (free, m136) for both BK=32 and BK=64.
// EPI: 0 = bf16 out; 1 = f32 out + bias + f32 residual (res MAY alias outp); 2 = bf16 out + bias + relu
template <int EPI, int TM, int TN, int BK>
__global__ __launch_bounds__(256) void gemm_bt(const u16* __restrict__ A, const u16* __restrict__ BT,
                                               const float* __restrict__ bias, const float* res,
                                               void* outp, int M, int N, int K) {
    constexpr int S = BK / 8;               // 16B segs per row
    constexpr int SM = S - 1;               // swizzle mask
    constexpr int MB_ = TM / 32;            // m-frags per wave
    constexpr int NB = TN / 32;             // n-frags per wave
    constexpr int KS = BK / 32;             // MFMA k sub-steps per K-step
    constexpr int ABUFB = TM * BK * 2;      // A buffer bytes
    constexpr int BBUFB = TN * BK * 2;      // B buffer bytes
    constexpr int ACH = (TM * S) / 256;     // A staging chunks per thread
    constexpr int BCH = (TN * S) / 256;     // B staging chunks per thread
    constexpr int PG = (MROWS / TM) / 8;    // row-panels per XCD
    __shared__ u16 As[2][TM * BK];
    __shared__ u16 Bs[2][TN * BK];
    const int t = threadIdx.x, w = t >> 6, lane = t & 63;
    const u32 id = blockIdx.x;
    const int xcd = (int)(id & 7), rem = (int)(id >> 3);
    const int by = xcd + (rem % PG) * 8;   // row-panel
    const int bx = rem / PG;               // col-tile
    const int m0 = by * TM, n0 = bx * TN;
    const int wr = w >> 1, wc = w & 1;
    const int la = lane & 15, lb = lane >> 4;
    f4v acc[MB_][NB] = {};

    const char* Ab = (const char*)A;
    const char* Bb = (const char*)BT;
    const size_t strideb = (size_t)K * 2;
    char* AsB = (char*)As;
    char* BsB = (char*)Bs;

    // staging source offsets, pre-swizzled (chunk c = t + 256*i -> LDS byte c*16)
    size_t asrc[ACH], bsrc[BCH];
#pragma unroll
    for (int i = 0; i < ACH; i++) {
        const int c = t + 256 * i, row = c / S, seg = c % S;
        asrc[i] = (size_t)(m0 + row) * strideb + (size_t)((seg ^ ((row >> 1) & SM)) * 16);
    }
#pragma unroll
    for (int i = 0; i < BCH; i++) {
        const int c = t + 256 * i, row = c / S, seg = c % S;
        bsrc[i] = (size_t)(n0 + row) * strideb + (size_t)((seg ^ ((row >> 1) & SM)) * 16);
    }

    // prologue: stage tile 0 into buffer 0
#pragma unroll
    for (int i = 0; i < ACH; i++) gload16(Ab + asrc[i], AsB + i * 4096 + w * 1024);
#pragma unroll
    for (int i = 0; i < BCH; i++) gload16(Bb + bsrc[i], BsB + i * 4096 + w * 1024);
    __syncthreads();

    int cur = 0;
    for (int k0 = 0; k0 < K; k0 += BK) {
        if (k0 + BK < K) {   // prefetch next K-step into other buffer
            const size_t ko = (size_t)(k0 + BK) * 2;
            const int ab = (cur ^ 1) * ABUFB;
            const int bb = (cur ^ 1) * BBUFB;
#pragma unroll
            for (int i = 0; i < ACH; i++) gload16(Ab + asrc[i] + ko, AsB + ab + i * 4096 + w * 1024);
#pragma unroll
            for (int i = 0; i < BCH; i++) gload16(Bb + bsrc[i] + ko, BsB + bb + i * 4096 + w * 1024);
        }
#pragma unroll
        for (int ks = 0; ks < KS; ks++) {
            s8v a[MB_], bfr[NB];
#pragma unroll
            for (int mi = 0; mi < MB_; mi++) {
                const int row = wr * (TM / 2) + mi * 16 + la;
                const int sp = (ks * 4 + lb) ^ ((row >> 1) & SM);
                a[mi] = *(const s8v*)&As[cur][(row * S + sp) * 8];
            }
#pragma unroll
            for (int ni = 0; ni < NB; ni++) {
                const int row = wc * (TN / 2) + ni * 16 + la;
                const int sp = (ks * 4 + lb) ^ ((row >> 1) & SM);
                bfr[ni] = *(const s8v*)&Bs[cur][(row * S + sp) * 8];
            }
#pragma unroll
            for (int mi = 0; mi < MB_; mi++)
#pragma unroll
                for (int ni = 0; ni < NB; ni++)
                    acc[mi][ni] = __builtin_amdgcn_mfma_f32_16x16x32_bf16(a[mi], bfr[ni], acc[mi][ni], 0, 0, 0);
        }
        __syncthreads();   // single barrier per K-step (drains prefetch vmcnt)
        cur ^= 1;
    }

    const int orow = m0 + wr * (TM / 2), ocol = n0 + wc * (TN / 2);
#pragma unroll
    for (int mi = 0; mi < MB_; mi++)
#pragma unroll
        for (int ni = 0; ni < NB; ni++)
#pragma unroll
            for (int j2 = 0; j2 < 4; j2++) {
                int r = orow + mi * 16 + lb * 4 + j2;
                int c = ocol + ni * 16 + la;
                float v = acc[mi][ni][j2];
                if (EPI == 0) {
                    ((u16*)outp)[(size_t)r * N + c] = f2bf(v);
                } else if (EPI == 1) {
                    ((float*)outp)[(size_t)r * N + c] = v + bias[c] + res[(size_t)r * N + c];
                } else {
                    v += bias[c];
                    ((u16*)outp)[(size_t)r * N + c] = f2bf(fmaxf(v, 0.f));
                }
            }
}

// ---------------- MFMA flash attention (causal), single-tile blocks, 2 blocks/CU ----------
// QKV: [MROWS][3072] bf16 (Q|K|V each 1024). O: [MROWS][1024] bf16.
// 512 blocks x 512 threads. Block = one (b,h,qt) q-tile of 128 rows; 8 waves x 16 rows.
// KV tiles of 64 keys -> nkv = 2*qt+2 steps. qt mapping pairs ids (i, i+256) to sum 34 steps
// per CU (two independent barrier domains per CU -> cross-block latency hiding, m114).
// Softmax: log2 domain; DEFER-MAX (THR=8, wave-ballot); per-lane l partials reduced in epilogue.
#define LDK 72   /* padded LDS row stride (bf16) */
#define QKSCL 0.18033688f   /* (1/8) * log2(e) */
__global__ __launch_bounds__(512) void fattn(const u16* __restrict__ QKV, u16* __restrict__ O) {
    const int t = threadIdx.x, w = t >> 6, lane = t & 63;
    const int la = lane & 15, lb = lane >> 4;
    const u32 id = blockIdx.x;          // 0..511
    const int bh = (int)((id & 7) * 4 + ((id >> 3) & 3));
    const int idx = (int)(id >> 5);     // 0..15
    const int qt = (idx < 8) ? (15 - idx) : (idx - 8);
    const int b = bh >> 4, h = bh & 15;

    __shared__ u16 K_lds[64 * LDK];
    __shared__ u16 Vt_lds[64 * LDK];
    __shared__ u16 P_lds[8][16 * LDK];

    const u16* base = QKV + (size_t)(b * SEQ) * 3072 + h * HDIM;
    const u16* Qg = base;
    const u16* Kg = base + 1024;
    const u16* Vg = base + 2048;
    u16* pw = &P_lds[w][0];

    // staging work split: K by all 512 threads (1 x s8v), V-transpose by threads 0..255 (2 x s8v)
    const int krow = t >> 3, kseg = t & 7;
    const int vss = (t >> 5) & 7, vkp = t & 31;
    const bool vstager = (t < 256);

    const int qbase = qt * 128;
    const int nkv = 2 * qt + 2;
    const int wq0 = qbase + w * 16;   // wave's first absolute q row

    // Q fragments
    s8v aq0, aq1;
    {
        const u16* qr = Qg + (size_t)(wq0 + la) * 3072 + lb * 8;
        aq0 = *(const s8v*)(qr);
        aq1 = *(const s8v*)(qr + 32);
    }
    float m[4], lp[4];   // running max (log2 domain) and PER-LANE l partials
#pragma unroll
    for (int j = 0; j < 4; j++) { m[j] = -1e30f; lp[j] = 0.f; }
    f4v oacc[4] = {};

    // prologue: prefetch tile 0 into registers
    s8v kstg, vstgA, vstgB;
    kstg = *(const s8v*)(Kg + (size_t)krow * 3072 + kseg * 8);
    if (vstager) {
        const u16* v0 = Vg + (size_t)(vkp * 2) * 3072 + vss * 8;
        vstgA = *(const s8v*)(v0);
        vstgB = *(const s8v*)(v0 + 3072);
    }

    for (int kt = 0; kt < nkv; ++kt) {
        const int kv0 = kt * 64;
        // write staged regs -> LDS (vmcnt wait auto-inserted on reg use)
        *(s8v*)&K_lds[krow * LDK + kseg * 8] = kstg;
        if (vstager) {
            u32* vt32 = (u32*)Vt_lds;
#pragma unroll
            for (int j2 = 0; j2 < 8; j2++)
                vt32[(vss * 8 + j2) * (LDK / 2) + vkp] =
                    (u32)(u16)vstgA[j2] | ((u32)(u16)vstgB[j2] << 16);
        }
        // async prefetch of next tile (in flight across the compute phase)
        if (kt + 1 < nkv) {
            const int nv0 = kv0 + 64;
            kstg = *(const s8v*)(Kg + (size_t)(nv0 + krow) * 3072 + kseg * 8);
            if (vstager) {
                const u16* v0 = Vg + (size_t)(nv0 + vkp * 2) * 3072 + vss * 8;
                vstgA = *(const s8v*)(v0);
                vstgB = *(const s8v*)(v0 + 3072);
            }
        }
        __syncthreads();

        if (kv0 <= wq0 + 15) {   // wave has at least one unmasked key in this tile
            // ---- QK^T ----
            f4v sacc[4] = {};
            __builtin_amdgcn_s_setprio(1);
#pragma unroll
            for (int kc = 0; kc < 4; kc++) {
                s8v bk0 = *(const s8v*)&K_lds[(kc * 16 + la) * LDK + lb * 8];
                s8v bk1 = *(const s8v*)&K_lds[(kc * 16 + la) * LDK + 32 + lb * 8];
                sacc[kc] = __builtin_amdgcn_mfma_f32_16x16x32_bf16(aq0, bk0, sacc[kc], 0, 0, 0);
                sacc[kc] = __builtin_amdgcn_mfma_f32_16x16x32_bf16(aq1, bk1, sacc[kc], 0, 0, 0);
            }
            __builtin_amdgcn_s_setprio(0);

            // ---- scale + mask (log2 domain), local max, defer-max ballot ----
            const bool doMask = (kv0 + 63 > wq0);
            float s[4][4];     // [kc][j]
            float mx[4];       // per-lane local max per row j
            bool ok = true;
#pragma unroll
            for (int j = 0; j < 4; j++) {
                const int row = wq0 + lb * 4 + j;
                float s0 = sacc[0][j] * QKSCL;
                float s1 = sacc[1][j] * QKSCL;
                float s2 = sacc[2][j] * QKSCL;
                float s3 = sacc[3][j] * QKSCL;
                if (doMask) {
                    if (kv0 + 0 * 16 + la > row) s0 = -1e30f;
                    if (kv0 + 1 * 16 + la > row) s1 = -1e30f;
                    if (kv0 + 2 * 16 + la > row) s2 = -1e30f;
                    if (kv0 + 3 * 16 + la > row) s3 = -1e30f;
                }
                s[0][j] = s0; s[1][j] = s1; s[2][j] = s2; s[3][j] = s3;
                float v = fmaxf(fmaxf(s0, s1), fmaxf(s2, s3));
                mx[j] = v;
                ok = ok && (v <= m[j] + 8.f);
            }
            if (__all(ok)) {
                // ---- common path: no cross-lane ops, no rescale ----
#pragma unroll
                for (int j = 0; j < 4; j++) {
                    float e0 = fexp2(s[0][j] - m[j]);
                    float e1 = fexp2(s[1][j] - m[j]);
                    float e2 = fexp2(s[2][j] - m[j]);
                    float e3 = fexp2(s[3][j] - m[j]);
                    lp[j] += (e0 + e1) + (e2 + e3);
                    u32 c01 = cvtpk_bf16(e0, e1);
                    u32 c23 = cvtpk_bf16(e2, e3);
                    u16* pr = pw + (lb * 4 + j) * LDK + la;
                    pr[0]  = (u16)c01;
                    pr[16] = (u16)(c01 >> 16);
                    pr[32] = (u16)c23;
                    pr[48] = (u16)(c23 >> 16);
                }
            } else {
                // ---- rescale path: full cross-lane max + rescale ----
#pragma unroll
                for (int j = 0; j < 4; j++) {
                    float v = mx[j];
                    v = fmaxf(v, __shfl_xor(v, 1));
                    v = fmaxf(v, __shfl_xor(v, 2));
                    v = fmaxf(v, __shfl_xor(v, 4));
                    v = fmaxf(v, __shfl_xor(v, 8));
                    float mn = fmaxf(m[j], v);
                    float sc = fexp2(m[j] - mn);
                    m[j] = mn;
                    lp[j] *= sc;
#pragma unroll
                    for (int dt = 0; dt < 4; dt++) oacc[dt][j] *= sc;
                    float e0 = fexp2(s[0][j] - mn);
                    float e1 = fexp2(s[1][j] - mn);
                    float e2 = fexp2(s[2][j] - mn);
                    float e3 = fexp2(s[3][j] - mn);
                    lp[j] += (e0 + e1) + (e2 + e3);
                    u32 c01 = cvtpk_bf16(e0, e1);
                    u32 c23 = cvtpk_bf16(e2, e3);
                    u16* pr = pw + (lb * 4 + j) * LDK + la;
                    pr[0]  = (u16)c01;
                    pr[16] = (u16)(c01 >> 16);
                    pr[32] = (u16)c23;
                    pr[48] = (u16)(c23 >> 16);
                }
            }

            // ---- PV: O += P @ V ----
            s8v ap0 = *(const s8v*)&pw[la * LDK + lb * 8];
            s8v ap1 = *(const s8v*)&pw[la * LDK + 32 + lb * 8];
            __builtin_amdgcn_s_setprio(1);
#pragma unroll
            for (int dt = 0; dt < 4; dt++) {
                s8v v0 = *(const s8v*)&Vt_lds[(dt * 16 + la) * LDK + lb * 8];
                s8v v1 = *(const s8v*)&Vt_lds[(dt * 16 + la) * LDK + 32 + lb * 8];
                oacc[dt] = __builtin_amdgcn_mfma_f32_16x16x32_bf16(ap0, v0, oacc[dt], 0, 0, 0);
                oacc[dt] = __builtin_amdgcn_mfma_f32_16x16x32_bf16(ap1, v1, oacc[dt], 0, 0, 0);
            }
            __builtin_amdgcn_s_setprio(0);
        }
        __syncthreads();
    }

    // ---- epilogue: reduce l partials across the 16 row-lanes, then write ----
    float l[4];
#pragma unroll
    for (int j = 0; j < 4; j++) {
        float rs = lp[j];
        rs += __shfl_xor(rs, 1);
        rs += __shfl_xor(rs, 2);
        rs += __shfl_xor(rs, 4);
        rs += __shfl_xor(rs, 8);
        l[j] = rs;
    }
#pragma unroll
    for (int dt = 0; dt < 4; dt++) {
#pragma unroll
        for (int j = 0; j < 4; j++) {
            const int q = wq0 + lb * 4 + j;
            O[(size_t)(b * SEQ + q) * EMB + h * HDIM + dt * 16 + la] = f2bf(oacc[dt][j] / l[j]);
        }
    }
}

extern "C" void kernel_launch(void* const* d_in, const int* in_sizes, int n_in,
                              void* d_out, int out_size, void* d_ws, size_t ws_size,
                              hipStream_t stream) {
    const float* x    = (const float*)d_in[0];
    const float* Wq   = (const float*)d_in[1];
    const float* Wk   = (const float*)d_in[2];
    const float* Wv   = (const float*)d_in[3];
    const float* Wo   = (const float*)d_in[4];
    const float* bo   = (const float*)d_in[5];
    const float* ln1w = (const float*)d_in[6];
    const float* ln1b = (const float*)d_in[7];
    const float* ln2w = (const float*)d_in[8];
    const float* ln2b = (const float*)d_in[9];
    const float* W1   = (const float*)d_in[10];
    const float* b1   = (const float*)d_in[11];
    const float* W2   = (const float*)d_in[12];
    const float* b2   = (const float*)d_in[13];

    // ---- workspace layout: exactly 64MB ----
    const size_t MB = 1024 * 1024;
    char* ws = (char*)d_ws;
    u16* WqkvT = (u16*)(ws);              // [3072][1024] bf16 = 6MB
    u16* WoT   = (u16*)(ws + 6 * MB);     // [1024][1024] = 2MB
    u16* W1T   = (u16*)(ws + 8 * MB);     // [4096][1024] = 8MB
    u16* W2T   = (u16*)(ws + 16 * MB);    // [1024][4096] = 8MB
    u16* xn    = (u16*)(ws + 24 * MB);    // [4096][1024] = 8MB
    u16* QKV   = (u16*)(ws + 32 * MB);    // [4096][3072] = 24MB
    u16* mid   = (u16*)(ws + 32 * MB);    // [4096][4096] = 32MB (reuses QKV region)
    u16* hn    = xn;                      // LN2 out reuses xn (dead after h-GEMM)
    float* hbuf = (float*)d_out;          // h lives in d_out (f32)

    // all 6 weight transposes in ONE launch (12288 tiles of 32x32)
    transpose_all<<<dim3(12288), dim3(32, 8), 0, stream>>>(
        Wq, Wk, Wv, Wo, W1, W2, WqkvT, WoT, W1T, W2T);

    ln_kernel<<<MROWS, 256, 0, stream>>>(x, ln1w, ln1b, xn);

    // QKV: [4096][3072]   128x128 tiles: grid = 24*32 = 768 blocks (3/CU)
    gemm_bt<0, 128, 128, 32><<<dim3((3072 / 128) * (MROWS / 128)), 256, 0, stream>>>(
        xn, WqkvT, nullptr, nullptr, QKV, MROWS, 3072, 1024);

    // flash attention -> xn (reuse; QKV fully consumed here); 512 blocks x 512 threads (2/CU)
    fattn<<<dim3(512), 512, 0, stream>>>(QKV, xn);

    // h = x + attn @ Wo + bo  -> d_out (f32)   64x64 tiles: grid = 16*64 = 1024 blocks (4/CU)
    gemm_bt<1, 64, 64, 64><<<dim3((1024 / 64) * (MROWS / 64)), 256, 0, stream>>>(
        xn, WoT, bo, x, hbuf, MROWS, 1024, 1024);

    // hn = LN2(h) (xn region is dead now)
    ln_kernel<<<MROWS, 256, 0, stream>>>(hbuf, ln2w, ln2b, hn);

    // mid = relu(hn @ W1 + b1)   128x128 tiles: grid = 32*32 = 1024 blocks (4/CU)
    gemm_bt<2, 128, 128, 32><<<dim3((HID / 128) * (MROWS / 128)), 256, 0, stream>>>(
        hn, W1T, b1, nullptr, mid, MROWS, HID, 1024);

    // out = h + mid @ W2 + b2  (in-place on d_out)   128x64 tiles, BK=32: grid = 512 (2/CU)
    gemm_bt<1, 128, 64, 32><<<dim3((1024 / 64) * (MROWS / 128)), 256, 0, stream>>>(
        mid, W2T, b2, hbuf, hbuf, MROWS, 1024, HID);
}

// Round 22
// 228.760 us; speedup vs baseline: 1.0862x; 1.0862x over previous
//
#include <hip/hip_runtime.h>

typedef unsigned short u16;
typedef unsigned int u32;
typedef __attribute__((ext_vector_type(8))) short s8v;   // 8 bf16 (4 VGPRs) MFMA A/B frag
typedef __attribute__((ext_vector_type(4))) float f4v;   // MFMA C/D frag

#define EMB 1024
#define SEQ 2048
#define BATCH 2
#define HEADS 16
#define HDIM 64
#define HID 4096
#define MROWS 4096   /* BATCH*SEQ */

__device__ __forceinline__ float bf2f(u16 h) {
    u32 u = ((u32)h) << 16;
    union { u32 u; float f; } v; v.u = u; return v.f;
}
__device__ __forceinline__ u16 f2bf(float f) {
    union { float f; u32 u; } v; v.f = f;
    u32 r = v.u + 0x7FFFu + ((v.u >> 16) & 1u);   // RNE
    return (u16)(r >> 16);
}
__device__ __forceinline__ float fexp2(float x) {   // raw v_exp_f32 (2^x)
    float r; asm("v_exp_f32 %0, %1" : "=v"(r) : "v"(x)); return r;
}
__device__ __forceinline__ u32 cvtpk_bf16(float lo, float hi) {   // 2xf32 -> packed bf16
    u32 r; asm("v_cvt_pk_bf16_f32 %0, %1, %2" : "=v"(r) : "v"(lo), "v"(hi)); return r;
}

__device__ __forceinline__ void gload16(const void* g, void* l) {
    __builtin_amdgcn_global_load_lds(
        (const __attribute__((address_space(1))) unsigned int*)g,
        (__attribute__((address_space(3))) unsigned int*)l, 16, 0, 0);
}

// -------- batched transpose + f32->bf16 cast for ALL weights in ONE launch --------
__global__ __launch_bounds__(256) void transpose_all(
        const float* __restrict__ Wq, const float* __restrict__ Wk,
        const float* __restrict__ Wv, const float* __restrict__ Wo,
        const float* __restrict__ W1, const float* __restrict__ W2,
        u16* __restrict__ WqkvT, u16* __restrict__ WoT,
        u16* __restrict__ W1T, u16* __restrict__ W2T) {
    __shared__ float tile[32][33];
    const u32 id = blockIdx.x;
    const float* W;
    u16* WT;
    int K, N, local;
    if (id < 3072) {
        W = (id < 1024) ? Wq : (id < 2048) ? Wk : Wv;
        WT = WqkvT + (size_t)(id >> 10) * 1024 * 1024;
        K = 1024; N = 1024; local = (int)(id & 1023);
    } else if (id < 4096) {
        W = Wo; WT = WoT; K = 1024; N = 1024; local = (int)(id - 3072);
    } else if (id < 8192) {
        W = W1; WT = W1T; K = 1024; N = 4096; local = (int)(id - 4096);
    } else {
        W = W2; WT = W2T; K = 4096; N = 1024; local = (int)(id - 8192);
    }
    const int nx = N / 32;
    const int n0 = (local % nx) * 32, k0 = (local / nx) * 32;
    const int tx = threadIdx.x, ty = threadIdx.y;   // 32 x 8
#pragma unroll
    for (int i = ty; i < 32; i += 8)
        tile[i][tx] = W[(size_t)(k0 + i) * N + n0 + tx];
    __syncthreads();
#pragma unroll
    for (int i = ty; i < 32; i += 8)
        WT[(size_t)(n0 + i) * K + k0 + tx] = f2bf(tile[tx][i]);
}

// ---------------- layernorm f32 -> bf16 ----------------
__global__ __launch_bounds__(256) void ln_kernel(const float* __restrict__ in,
                                                 const float* __restrict__ w,
                                                 const float* __restrict__ b,
                                                 u16* __restrict__ out) {
    const int row = blockIdx.x, t = threadIdx.x;
    const float4* rp = (const float4*)(in + (size_t)row * EMB);
    float4 v = rp[t];
    float s = v.x + v.y + v.z + v.w;
    __shared__ float red[4];
#pragma unroll
    for (int off = 32; off; off >>= 1) s += __shfl_xor(s, off);
    if ((t & 63) == 0) red[t >> 6] = s;
    __syncthreads();
    float mean = (red[0] + red[1] + red[2] + red[3]) * (1.f / EMB);
    float dx = v.x - mean, dy = v.y - mean, dz = v.z - mean, dw = v.w - mean;
    float ss = dx * dx + dy * dy + dz * dz + dw * dw;
#pragma unroll
    for (int off = 32; off; off >>= 1) ss += __shfl_xor(ss, off);
    __syncthreads();
    if ((t & 63) == 0) red[t >> 6] = ss;
    __syncthreads();
    float var = (red[0] + red[1] + red[2] + red[3]) * (1.f / EMB);
    float rstd = rsqrtf(var + 1e-5f);
    float4 wv = ((const float4*)w)[t];
    float4 bv = ((const float4*)b)[t];
    u16* op = out + (size_t)row * EMB + t * 4;
    op[0] = f2bf(dx * rstd * wv.x + bv.x);
    op[1] = f2bf(dy * rstd * wv.y + bv.y);
    op[2] = f2bf(dz * rstd * wv.z + bv.z);
    op[3] = f2bf(dw * rstd * wv.w + bv.w);
}

// ------- bf16 MFMA GEMM, TMxTN tiles, BK-step, dbuf, XCD-swizzled, 2-way LDS swizzle -------
// C[M,N] = A[M,K] @ BT[N,K]^T.  Grid = (N/TN)*(MROWS/TM) blocks, 4 waves in 2x2.
// LDS: linear dest (gload_lds requirement); contents XOR-swizzled via the GLOBAL SOURCE:
//   physical seg = seg ^ ((row>>1) & SM); reads apply the same XOR -> exactly 2-way bank
//   aliasing (free, m136) for both BK=32 and BK=64.
// EPI: 0 = bf16 out; 1 = f32 out + bias + f32 residual (res MAY alias outp); 2 = bf16 out + bias + relu
template <int EPI, int TM, int TN, int BK>
__global__ __launch_bounds__(256) void gemm_bt(const u16* __restrict__ A, const u16* __restrict__ BT,
                                               const float* __restrict__ bias, const float* res,
                                               void* outp, int M, int N, int K) {
    constexpr int S = BK / 8;               // 16B segs per row
    constexpr int SM = S - 1;               // swizzle mask
    constexpr int MB_ = TM / 32;            // m-frags per wave
    constexpr int NB = TN / 32;             // n-frags per wave
    constexpr int KS = BK / 32;             // MFMA k sub-steps per K-step
    constexpr int ABUFB = TM * BK * 2;      // A buffer bytes
    constexpr int BBUFB = TN * BK * 2;      // B buffer bytes
    constexpr int ACH = (TM * S) / 256;     // A staging chunks per thread
    constexpr int BCH = (TN * S) / 256;     // B staging chunks per thread
    constexpr int PG = (MROWS / TM) / 8;    // row-panels per XCD
    __shared__ u16 As[2][TM * BK];
    __shared__ u16 Bs[2][TN * BK];
    const int t = threadIdx.x, w = t >> 6, lane = t & 63;
    const u32 id = blockIdx.x;
    const int xcd = (int)(id & 7), rem = (int)(id >> 3);
    const int by = xcd + (rem % PG) * 8;   // row-panel
    const int bx = rem / PG;               // col-tile
    const int m0 = by * TM, n0 = bx * TN;
    const int wr = w >> 1, wc = w & 1;
    const int la = lane & 15, lb = lane >> 4;
    f4v acc[MB_][NB] = {};

    const char* Ab = (const char*)A;
    const char* Bb = (const char*)BT;
    const size_t strideb = (size_t)K * 2;
    char* AsB = (char*)As;
    char* BsB = (char*)Bs;

    // staging source offsets, pre-swizzled (chunk c = t + 256*i -> LDS byte c*16)
    size_t asrc[ACH], bsrc[BCH];
#pragma unroll
    for (int i = 0; i < ACH; i++) {
        const int c = t + 256 * i, row = c / S, seg = c % S;
        asrc[i] = (size_t)(m0 + row) * strideb + (size_t)((seg ^ ((row >> 1) & SM)) * 16);
    }
#pragma unroll
    for (int i = 0; i < BCH; i++) {
        const int c = t + 256 * i, row = c / S, seg = c % S;
        bsrc[i] = (size_t)(n0 + row) * strideb + (size_t)((seg ^ ((row >> 1) & SM)) * 16);
    }

    // prologue: stage tile 0 into buffer 0
#pragma unroll
    for (int i = 0; i < ACH; i++) gload16(Ab + asrc[i], AsB + i * 4096 + w * 1024);
#pragma unroll
    for (int i = 0; i < BCH; i++) gload16(Bb + bsrc[i], BsB + i * 4096 + w * 1024);
    __syncthreads();

    int cur = 0;
    for (int k0 = 0; k0 < K; k0 += BK) {
        if (k0 + BK < K) {   // prefetch next K-step into other buffer
            const size_t ko = (size_t)(k0 + BK) * 2;
            const int ab = (cur ^ 1) * ABUFB;
            const int bb = (cur ^ 1) * BBUFB;
#pragma unroll
            for (int i = 0; i < ACH; i++) gload16(Ab + asrc[i] + ko, AsB + ab + i * 4096 + w * 1024);
#pragma unroll
            for (int i = 0; i < BCH; i++) gload16(Bb + bsrc[i] + ko, BsB + bb + i * 4096 + w * 1024);
        }
#pragma unroll
        for (int ks = 0; ks < KS; ks++) {
            s8v a[MB_], bfr[NB];
#pragma unroll
            for (int mi = 0; mi < MB_; mi++) {
                const int row = wr * (TM / 2) + mi * 16 + la;
                const int sp = (ks * 4 + lb) ^ ((row >> 1) & SM);
                a[mi] = *(const s8v*)&As[cur][(row * S + sp) * 8];
            }
#pragma unroll
            for (int ni = 0; ni < NB; ni++) {
                const int row = wc * (TN / 2) + ni * 16 + la;
                const int sp = (ks * 4 + lb) ^ ((row >> 1) & SM);
                bfr[ni] = *(const s8v*)&Bs[cur][(row * S + sp) * 8];
            }
#pragma unroll
            for (int mi = 0; mi < MB_; mi++)
#pragma unroll
                for (int ni = 0; ni < NB; ni++)
                    acc[mi][ni] = __builtin_amdgcn_mfma_f32_16x16x32_bf16(a[mi], bfr[ni], acc[mi][ni], 0, 0, 0);
        }
        __syncthreads();   // single barrier per K-step (drains prefetch vmcnt)
        cur ^= 1;
    }

    const int orow = m0 + wr * (TM / 2), ocol = n0 + wc * (TN / 2);
#pragma unroll
    for (int mi = 0; mi < MB_; mi++)
#pragma unroll
        for (int ni = 0; ni < NB; ni++)
#pragma unroll
            for (int j2 = 0; j2 < 4; j2++) {
                int r = orow + mi * 16 + lb * 4 + j2;
                int c = ocol + ni * 16 + la;
                float v = acc[mi][ni][j2];
                if (EPI == 0) {
                    ((u16*)outp)[(size_t)r * N + c] = f2bf(v);
                } else if (EPI == 1) {
                    ((float*)outp)[(size_t)r * N + c] = v + bias[c] + res[(size_t)r * N + c];
                } else {
                    v += bias[c];
                    ((u16*)outp)[(size_t)r * N + c] = f2bf(fmaxf(v, 0.f));
                }
            }
}

// ---------------- MFMA flash attention (causal), single-tile blocks, 2 blocks/CU ----------
// QKV: [MROWS][3072] bf16 (Q|K|V each 1024). O: [MROWS][1024] bf16.
// 512 blocks x 512 threads. Block = one (b,h,qt) q-tile of 128 rows; 8 waves x 16 rows.
// KV tiles of 64 keys -> nkv = 2*qt+2 steps. qt mapping pairs ids (i, i+256) to sum 34 steps
// per CU (two independent barrier domains per CU -> cross-block latency hiding, m114).
// Softmax: log2 domain; DEFER-MAX (THR=8, wave-ballot); per-lane l partials reduced in epilogue.
#define LDK 72   /* padded LDS row stride (bf16) */
#define QKSCL 0.18033688f   /* (1/8) * log2(e) */
__global__ __launch_bounds__(512) void fattn(const u16* __restrict__ QKV, u16* __restrict__ O) {
    const int t = threadIdx.x, w = t >> 6, lane = t & 63;
    const int la = lane & 15, lb = lane >> 4;
    const u32 id = blockIdx.x;          // 0..511
    const int bh = (int)((id & 7) * 4 + ((id >> 3) & 3));
    const int idx = (int)(id >> 5);     // 0..15
    const int qt = (idx < 8) ? (15 - idx) : (idx - 8);
    const int b = bh >> 4, h = bh & 15;

    __shared__ u16 K_lds[64 * LDK];
    __shared__ u16 Vt_lds[64 * LDK];
    __shared__ u16 P_lds[8][16 * LDK];

    const u16* base = QKV + (size_t)(b * SEQ) * 3072 + h * HDIM;
    const u16* Qg = base;
    const u16* Kg = base + 1024;
    const u16* Vg = base + 2048;
    u16* pw = &P_lds[w][0];

    // staging work split: K by all 512 threads (1 x s8v), V-transpose by threads 0..255 (2 x s8v)
    const int krow = t >> 3, kseg = t & 7;
    const int vss = (t >> 5) & 7, vkp = t & 31;
    const bool vstager = (t < 256);

    const int qbase = qt * 128;
    const int nkv = 2 * qt + 2;
    const int wq0 = qbase + w * 16;   // wave's first absolute q row

    // Q fragments
    s8v aq0, aq1;
    {
        const u16* qr = Qg + (size_t)(wq0 + la) * 3072 + lb * 8;
        aq0 = *(const s8v*)(qr);
        aq1 = *(const s8v*)(qr + 32);
    }
    float m[4], lp[4];   // running max (log2 domain) and PER-LANE l partials
#pragma unroll
    for (int j = 0; j < 4; j++) { m[j] = -1e30f; lp[j] = 0.f; }
    f4v oacc[4] = {};

    // prologue: prefetch tile 0 into registers
    s8v kstg, vstgA, vstgB;
    kstg = *(const s8v*)(Kg + (size_t)krow * 3072 + kseg * 8);
    if (vstager) {
        const u16* v0 = Vg + (size_t)(vkp * 2) * 3072 + vss * 8;
        vstgA = *(const s8v*)(v0);
        vstgB = *(const s8v*)(v0 + 3072);
    }

    for (int kt = 0; kt < nkv; ++kt) {
        const int kv0 = kt * 64;
        // write staged regs -> LDS (vmcnt wait auto-inserted on reg use)
        *(s8v*)&K_lds[krow * LDK + kseg * 8] = kstg;
        if (vstager) {
            u32* vt32 = (u32*)Vt_lds;
#pragma unroll
            for (int j2 = 0; j2 < 8; j2++)
                vt32[(vss * 8 + j2) * (LDK / 2) + vkp] =
                    (u32)(u16)vstgA[j2] | ((u32)(u16)vstgB[j2] << 16);
        }
        // async prefetch of next tile (in flight across the compute phase)
        if (kt + 1 < nkv) {
            const int nv0 = kv0 + 64;
            kstg = *(const s8v*)(Kg + (size_t)(nv0 + krow) * 3072 + kseg * 8);
            if (vstager) {
                const u16* v0 = Vg + (size_t)(nv0 + vkp * 2) * 3072 + vss * 8;
                vstgA = *(const s8v*)(v0);
                vstgB = *(const s8v*)(v0 + 3072);
            }
        }
        __syncthreads();

        if (kv0 <= wq0 + 15) {   // wave has at least one unmasked key in this tile
            // ---- QK^T ----
            f4v sacc[4] = {};
            __builtin_amdgcn_s_setprio(1);
#pragma unroll
            for (int kc = 0; kc < 4; kc++) {
                s8v bk0 = *(const s8v*)&K_lds[(kc * 16 + la) * LDK + lb * 8];
                s8v bk1 = *(const s8v*)&K_lds[(kc * 16 + la) * LDK + 32 + lb * 8];
                sacc[kc] = __builtin_amdgcn_mfma_f32_16x16x32_bf16(aq0, bk0, sacc[kc], 0, 0, 0);
                sacc[kc] = __builtin_amdgcn_mfma_f32_16x16x32_bf16(aq1, bk1, sacc[kc], 0, 0, 0);
            }
            __builtin_amdgcn_s_setprio(0);

            // ---- scale + mask (log2 domain), local max, defer-max ballot ----
            const bool doMask = (kv0 + 63 > wq0);
            float s[4][4];     // [kc][j]
            float mx[4];       // per-lane local max per row j
            bool ok = true;
#pragma unroll
            for (int j = 0; j < 4; j++) {
                const int row = wq0 + lb * 4 + j;
                float s0 = sacc[0][j] * QKSCL;
                float s1 = sacc[1][j] * QKSCL;
                float s2 = sacc[2][j] * QKSCL;
                float s3 = sacc[3][j] * QKSCL;
                if (doMask) {
                    if (kv0 + 0 * 16 + la > row) s0 = -1e30f;
                    if (kv0 + 1 * 16 + la > row) s1 = -1e30f;
                    if (kv0 + 2 * 16 + la > row) s2 = -1e30f;
                    if (kv0 + 3 * 16 + la > row) s3 = -1e30f;
                }
                s[0][j] = s0; s[1][j] = s1; s[2][j] = s2; s[3][j] = s3;
                float v = fmaxf(fmaxf(s0, s1), fmaxf(s2, s3));
                mx[j] = v;
                ok = ok && (v <= m[j] + 8.f);
            }
            if (__all(ok)) {
                // ---- common path: no cross-lane ops, no rescale ----
#pragma unroll
                for (int j = 0; j < 4; j++) {
                    float e0 = fexp2(s[0][j] - m[j]);
                    float e1 = fexp2(s[1][j] - m[j]);
                    float e2 = fexp2(s[2][j] - m[j]);
                    float e3 = fexp2(s[3][j] - m[j]);
                    lp[j] += (e0 + e1) + (e2 + e3);
                    u32 c01 = cvtpk_bf16(e0, e1);
                    u32 c23 = cvtpk_bf16(e2, e3);
                    u16* pr = pw + (lb * 4 + j) * LDK + la;
                    pr[0]  = (u16)c01;
                    pr[16] = (u16)(c01 >> 16);
                    pr[32] = (u16)c23;
                    pr[48] = (u16)(c23 >> 16);
                }
            } else {
                // ---- rescale path: full cross-lane max + rescale ----
#pragma unroll
                for (int j = 0; j < 4; j++) {
                    float v = mx[j];
                    v = fmaxf(v, __shfl_xor(v, 1));
                    v = fmaxf(v, __shfl_xor(v, 2));
                    v = fmaxf(v, __shfl_xor(v, 4));
                    v = fmaxf(v, __shfl_xor(v, 8));
                    float mn = fmaxf(m[j], v);
                    float sc = fexp2(m[j] - mn);
                    m[j] = mn;
                    lp[j] *= sc;
#pragma unroll
                    for (int dt = 0; dt < 4; dt++) oacc[dt][j] *= sc;
                    float e0 = fexp2(s[0][j] - mn);
                    float e1 = fexp2(s[1][j] - mn);
                    float e2 = fexp2(s[2][j] - mn);
                    float e3 = fexp2(s[3][j] - mn);
                    lp[j] += (e0 + e1) + (e2 + e3);
                    u32 c01 = cvtpk_bf16(e0, e1);
                    u32 c23 = cvtpk_bf16(e2, e3);
                    u16* pr = pw + (lb * 4 + j) * LDK + la;
                    pr[0]  = (u16)c01;
                    pr[16] = (u16)(c01 >> 16);
                    pr[32] = (u16)c23;
                    pr[48] = (u16)(c23 >> 16);
                }
            }

            // ---- PV: O += P @ V ----
            s8v ap0 = *(const s8v*)&pw[la * LDK + lb * 8];
            s8v ap1 = *(const s8v*)&pw[la * LDK + 32 + lb * 8];
            __builtin_amdgcn_s_setprio(1);
#pragma unroll
            for (int dt = 0; dt < 4; dt++) {
                s8v v0 = *(const s8v*)&Vt_lds[(dt * 16 + la) * LDK + lb * 8];
                s8v v1 = *(const s8v*)&Vt_lds[(dt * 16 + la) * LDK + 32 + lb * 8];
                oacc[dt] = __builtin_amdgcn_mfma_f32_16x16x32_bf16(ap0, v0, oacc[dt], 0, 0, 0);
                oacc[dt] = __builtin_amdgcn_mfma_f32_16x16x32_bf16(ap1, v1, oacc[dt], 0, 0, 0);
            }
            __builtin_amdgcn_s_setprio(0);
        }
        __syncthreads();
    }

    // ---- epilogue: reduce l partials across the 16 row-lanes, then write ----
    float l[4];
#pragma unroll
    for (int j = 0; j < 4; j++) {
        float rs = lp[j];
        rs += __shfl_xor(rs, 1);
        rs += __shfl_xor(rs, 2);
        rs += __shfl_xor(rs, 4);
        rs += __shfl_xor(rs, 8);
        l[j] = rs;
    }
#pragma unroll
    for (int dt = 0; dt < 4; dt++) {
#pragma unroll
        for (int j = 0; j < 4; j++) {
            const int q = wq0 + lb * 4 + j;
            O[(size_t)(b * SEQ + q) * EMB + h * HDIM + dt * 16 + la] = f2bf(oacc[dt][j] / l[j]);
        }
    }
}

extern "C" void kernel_launch(void* const* d_in, const int* in_sizes, int n_in,
                              void* d_out, int out_size, void* d_ws, size_t ws_size,
                              hipStream_t stream) {
    const float* x    = (const float*)d_in[0];
    const float* Wq   = (const float*)d_in[1];
    const float* Wk   = (const float*)d_in[2];
    const float* Wv   = (const float*)d_in[3];
    const float* Wo   = (const float*)d_in[4];
    const float* bo   = (const float*)d_in[5];
    const float* ln1w = (const float*)d_in[6];
    const float* ln1b = (const float*)d_in[7];
    const float* ln2w = (const float*)d_in[8];
    const float* ln2b = (const float*)d_in[9];
    const float* W1   = (const float*)d_in[10];
    const float* b1   = (const float*)d_in[11];
    const float* W2   = (const float*)d_in[12];
    const float* b2   = (const float*)d_in[13];

    // ---- workspace layout: exactly 64MB ----
    const size_t MB = 1024 * 1024;
    char* ws = (char*)d_ws;
    u16* WqkvT = (u16*)(ws);              // [3072][1024] bf16 = 6MB
    u16* WoT   = (u16*)(ws + 6 * MB);     // [1024][1024] = 2MB
    u16* W1T   = (u16*)(ws + 8 * MB);     // [4096][1024] = 8MB
    u16* W2T   = (u16*)(ws + 16 * MB);    // [1024][4096] = 8MB
    u16* xn    = (u16*)(ws + 24 * MB);    // [4096][1024] = 8MB
    u16* QKV   = (u16*)(ws + 32 * MB);    // [4096][3072] = 24MB
    u16* mid   = (u16*)(ws + 32 * MB);    // [4096][4096] = 32MB (reuses QKV region)
    u16* hn    = xn;                      // LN2 out reuses xn (dead after h-GEMM)
    float* hbuf = (float*)d_out;          // h lives in d_out (f32)

    // all 6 weight transposes in ONE launch (12288 tiles of 32x32)
    transpose_all<<<dim3(12288), dim3(32, 8), 0, stream>>>(
        Wq, Wk, Wv, Wo, W1, W2, WqkvT, WoT, W1T, W2T);

    ln_kernel<<<MROWS, 256, 0, stream>>>(x, ln1w, ln1b, xn);

    // QKV: [4096][3072]   128x128 tiles: grid = 24*32 = 768 blocks (3/CU)
    gemm_bt<0, 128, 128, 32><<<dim3((3072 / 128) * (MROWS / 128)), 256, 0, stream>>>(
        xn, WqkvT, nullptr, nullptr, QKV, MROWS, 3072, 1024);

    // flash attention -> xn (reuse; QKV fully consumed here); 512 blocks x 512 threads (2/CU)
    fattn<<<dim3(512), 512, 0, stream>>>(QKV, xn);

    // h = x + attn @ Wo + bo  -> d_out (f32)   64x64 tiles: grid = 16*64 = 1024 blocks (4/CU)
    gemm_bt<1, 64, 64, 64><<<dim3((1024 / 64) * (MROWS / 64)), 256, 0, stream>>>(
        xn, WoT, bo, x, hbuf, MROWS, 1024, 1024);

    // hn = LN2(h) (xn region is dead now)
    ln_kernel<<<MROWS, 256, 0, stream>>>(hbuf, ln2w, ln2b, hn);

    // mid = relu(hn @ W1 + b1)   128x128 tiles: grid = 32*32 = 1024 blocks (4/CU)
    gemm_bt<2, 128, 128, 32><<<dim3((HID / 128) * (MROWS / 128)), 256, 0, stream>>>(
        hn, W1T, b1, nullptr, mid, MROWS, HID, 1024);

    // out = h + mid @ W2 + b2  (in-place on d_out)   64x64 tiles: grid = 1024 blocks (4/CU)
    gemm_bt<1, 64, 64, 64><<<dim3((1024 / 64) * (MROWS / 64)), 256, 0, stream>>>(
        mid, W2T, b2, hbuf, hbuf, MROWS, 1024, HID);
}